// Round 19
// baseline (261.866 us; speedup 1.0000x reference)
//
#include <hip/hip_runtime.h>
#include <math.h>

#define NBATCH 262144
#define INVSQH 0.08838834764831845f   // 1/sqrt(128)

#define LROW  1088                    // table rows per layer
#define NGRID 1088                    // grid points: 192 coarse | 704 dense | 192 coarse
#define TROW  24

// ---- workspace layout (bytes) ----
#define WT_OFF   0          // Wres transposed [sidx][k][u] f32: 4,194,304
#define WFT_OFF  4194304    // WfT [L][k][32] f32 (o>=23 zero): 262,144
#define WS0_OFF  4456448    // W0 col0 [L][128] f32: 8,192
#define TAB_OFF  4464640    // knot table [L][1088][24] f32: cw1..8|ch1..8|d1..7|gridv
#define REC_OFF  7610368    // 16*40 f32
#define LDC_OFF  7612928    // 1 f32

// ---- fast approx ops (<=2 ulp; margin vs threshold ~9x) ----
__device__ __forceinline__ float fastrcp(float x) {
#if __has_builtin(__builtin_amdgcn_rcpf)
    return __builtin_amdgcn_rcpf(x);
#else
    return 1.f / x;
#endif
}
__device__ __forceinline__ float fastdiv(float a, float b) { return a * fastrcp(b); }
__device__ __forceinline__ float fastsqrt(float x) {
#if __has_builtin(__builtin_amdgcn_sqrtf)
    return __builtin_amdgcn_sqrtf(x);
#else
    return sqrtf(x);
#endif
}

__device__ __forceinline__ float softplusf(float x) {
    return (x > 15.f) ? x : __logf(1.f + __expf(x));
}

// implicit sorted grid: low coarse(192 @0.25) | dense(704 @0.025) | high coarse(192 @0.25)
__device__ __forceinline__ float gridval(int i) {
    float v = -56.8f + i * 0.25f;
    if (i >= 192) v = -8.8f + (i - 192) * 0.025f;
    if (i >= 896) v = 9.05f + (i - 896) * 0.25f;
    return v;
}
// closed-form count of grid values <= x; off-by-one benign (t from stored endpoints)
__device__ __forceinline__ int cnt_grid_le_fast(float x) {
    if (x < -56.8f) return 0;
    if (x < -8.8f)  return min((int)floorf((x + 56.8f) * 4.0f) + 1, 192);
    if (x < 9.05f)  return 192 + min((int)floorf((x + 8.8f) * 40.0f) + 1, 704);
    return 896 + min((int)floorf((x - 9.05f) * 4.0f) + 1, 192);
}

__device__ __forceinline__ void rqs_solve(float y, float yc, float yk, float hk, float xk,
                                          float wk, float dk, float dk1,
                                          float& xout, float& ldout)
{
    float sk = fastdiv(hk, wk);
    float dy = yc - yk;
    float t2 = dk + dk1 - 2.f * sk;
    float av = dy * t2 + hk * (sk - dk);
    float bv = hk * dk - dy * t2;
    float cv = -sk * dy;
    float disc = fmaxf(bv * bv - 4.f * av * cv, 0.f);
    float theta = 2.f * cv * fastrcp(-bv - fastsqrt(disc));
    float xo = fmaf(theta, wk, xk);
    float om = 1.f - theta;
    float denom = fmaf(t2, theta * om, sk);
    float dnum = sk * sk * (dk1 * theta * theta + 2.f * sk * theta * om + dk * om * om);
    float rden = fastrcp(denom);
    float ldf = __logf(dnum * rden * rden);       // log(dnum) - 2 log(denom)
    bool inside = (y >= -3.f) && (y <= 3.f);
    xout  = inside ? xo : y;
    ldout = inside ? -ldf : 0.f;
}

// knots from raw params p[0..22] (eval's knot phase)
__device__ __forceinline__ void knots_from_p(const float* __restrict__ p,
                                             float* __restrict__ cw,
                                             float* __restrict__ ch,
                                             float* __restrict__ d)
{
    float uw[8], uh[8];
#pragma unroll
    for (int j = 0; j < 8; ++j) uw[j] = p[j] * INVSQH;
#pragma unroll
    for (int j = 0; j < 8; ++j) uh[j] = p[8 + j] * INVSQH;
    float mw = uw[0], mh = uh[0];
#pragma unroll
    for (int j = 1; j < 8; ++j) { mw = fmaxf(mw, uw[j]); mh = fmaxf(mh, uh[j]); }
    float ew[8], eh[8], sw = 0.f, sh = 0.f;
#pragma unroll
    for (int j = 0; j < 8; ++j) {
        ew[j] = __expf(uw[j] - mw); sw += ew[j];
        eh[j] = __expf(uh[j] - mh); sh += eh[j];
    }
    float isw = 0.992f * fastrcp(sw), ish = 0.992f * fastrcp(sh);
    cw[0] = -3.f; ch[0] = -3.f;
    float aw = 0.f, ah = 0.f;
#pragma unroll
    for (int j = 0; j < 8; ++j) {
        aw += 0.001f + ew[j] * isw;
        ah += 0.001f + eh[j] * ish;
        cw[j + 1] = 6.f * aw - 3.f;
        ch[j + 1] = 6.f * ah - 3.f;
    }
    cw[8] = 3.f; ch[8] = 3.f;
    d[0] = 1.f; d[8] = 1.f;
#pragma unroll
    for (int j = 0; j < 7; ++j) d[j + 1] = 0.001f + softplusf(p[16 + j]);
}

__device__ __forceinline__ void rqs_from_knots(float y, const float* __restrict__ cw,
                                               const float* __restrict__ ch,
                                               const float* __restrict__ d,
                                               float& xout, float& ldout)
{
    float yc = fminf(fmaxf(y, -3.f), 3.f);
    float yk = ch[0], hk = ch[1] - ch[0], xk = cw[0], wk = cw[1] - cw[0];
    float dk = d[0], dk1 = d[1];
#pragma unroll
    for (int j = 1; j < 8; ++j) {
        bool cge = (yc >= ch[j]);
        yk  = cge ? ch[j] : yk;
        hk  = cge ? (ch[j + 1] - ch[j]) : hk;
        xk  = cge ? cw[j] : xk;
        wk  = cge ? (cw[j + 1] - cw[j]) : wk;
        dk  = cge ? d[j] : dk;
        dk1 = cge ? d[j + 1] : dk1;
    }
    rqs_solve(y, yc, yk, hk, xk, wk, dk, dk1, xout, ldout);
}

__device__ __forceinline__ void rqs_knots(float y, const float* __restrict__ rec,
                                          float& xout, float& ldout)
{
    rqs_from_knots(y, rec, rec + 9, rec + 18, xout, ldout);
}

// ------------- kernel 1: weight images (LDS-tiled transpose) + per-layer constants -------------
extern "C" __global__ __launch_bounds__(256)
void nsf_prep(const float* __restrict__ Wresg, const float* __restrict__ Wfg,
              const float* __restrict__ W0g,  const float* __restrict__ b0g,
              const float* __restrict__ bfg,
              const float* __restrict__ lulg, const float* __restrict__ luug,
              const float* __restrict__ ludg, const float* __restrict__ lubg,
              const int* __restrict__ permsg, char* __restrict__ ws)
{
    const int b = blockIdx.x, tid = threadIdx.x;
    float* WT  = (float*)(ws + WT_OFF);
    float* WFT = (float*)(ws + WFT_OFF);
    float* ws0 = (float*)(ws + WS0_OFF);

    if (b < 256) {
        __shared__ float T[64][65];
        const int mat = b >> 2, tr = (b >> 1) & 1, tc = b & 1;
        const float* src = Wresg + mat * 16384;
        float* dst = WT + mat * 16384;
        const int r = tid >> 2, q = tid & 3;        // 64 rows x 4 lanes/row
#pragma unroll
        for (int i = 0; i < 4; ++i) {
            int c4 = q * 4 + i;
            float4 v = *(const float4*)(src + (tr * 64 + r) * 128 + tc * 64 + c4 * 4);
            T[r][c4 * 4 + 0] = v.x; T[r][c4 * 4 + 1] = v.y;
            T[r][c4 * 4 + 2] = v.z; T[r][c4 * 4 + 3] = v.w;
        }
        __syncthreads();
        const int kk = tid >> 2;
#pragma unroll
        for (int i = 0; i < 4; ++i) {
            int u4 = q * 4 + i;
            float4 v;
            v.x = T[u4 * 4 + 0][kk]; v.y = T[u4 * 4 + 1][kk];
            v.z = T[u4 * 4 + 2][kk]; v.w = T[u4 * 4 + 3][kk];
            *(float4*)(dst + (tc * 64 + kk) * 128 + tr * 64 + u4 * 4) = v;
        }
        return;
    }

    const int L = b - 256;
    for (int e = tid; e < 4096; e += 256) {
        int k = e >> 5, o = e & 31;
        WFT[L * 4096 + e] = (o < 23) ? Wfg[(L * 46 + 23 + o) * 128 + k] : 0.f;
    }
    if (tid < 128) ws0[L * 128 + tid] = W0g[L * 256 + 2 * tid];

    if (tid == 0) {
        float* rec = (float*)(ws + REC_OFF) + L * 40;
        const float* p = bfg + L * 46;
        for (int half = 0; half < 2; ++half) {
            float u[8], m = -1e30f;
            for (int j = 0; j < 8; ++j) { u[j] = p[half * 8 + j] * INVSQH; m = fmaxf(m, u[j]); }
            float e[8], ssum = 0.f;
            for (int j = 0; j < 8; ++j) { e[j] = expf(u[j] - m); ssum += e[j]; }
            float cum = 0.f;
            rec[half * 9 + 0] = -3.f;
            for (int j = 0; j < 8; ++j) {
                cum += 0.001f + 0.992f * e[j] / ssum;
                rec[half * 9 + 1 + j] = 6.f * cum - 3.f;
            }
            rec[half * 9 + 8] = 3.f;
        }
        rec[18] = 1.f; rec[26] = 1.f;
        for (int j = 0; j < 7; ++j) {
            float x = p[16 + j];
            rec[19 + j] = 0.001f + ((x > 15.f) ? x : log1pf(expf(x)));
        }
        float x0 = ludg[2 * L], x1 = ludg[2 * L + 1];
        float dg0 = 0.001f + ((x0 > 15.f) ? x0 : log1pf(expf(x0)));
        float dg1 = 0.001f + ((x1 > 15.f) ? x1 : log1pf(expf(x1)));
        float ll = lulg[L], uu = luug[L];
        float det = dg0 * dg1;
        float c00 = (ll * uu + dg1) / det, c01 = -uu / det;
        float c10 = -ll / dg1, c11 = 1.f / dg1;
        int pa = permsg[2 * L], pb2 = permsg[2 * L + 1];
        rec[27] = pa ? c10 : c00;  rec[28] = pa ? c11 : c01;
        rec[29] = pb2 ? c10 : c00; rec[30] = pb2 ? c11 : c01;
        rec[31] = lubg[2 * L];     rec[32] = lubg[2 * L + 1];
    }
    if (L == 0 && tid == 32) {
        float ssum = 0.f;
        for (int l2 = 0; l2 < 16; ++l2) {
            float x0 = ludg[2 * l2], x1 = ludg[2 * l2 + 1];
            float dg0 = 0.001f + ((x0 > 15.f) ? x0 : log1pf(expf(x0)));
            float dg1 = 0.001f + ((x1 > 15.f) ? x1 : log1pf(expf(x1)));
            ssum += logf(dg0) + logf(dg1);
        }
        *(float*)(ws + LDC_OFF) = ssum;
    }
}

// ------------- kernel 2: table evaluation (grid -> knots), 4u x 4p threads -------------
// 544 blocks = 16 layers x 34 chunks of 32 points. Wave w owns u in [32w, 32w+32):
// thread u0 = w*32 + (lane&7)*4 (4 outputs), p0 = (lane>>3)*4 (4 points).
extern "C" __global__ __launch_bounds__(256, 4)
void nsf_eval(const float* __restrict__ bresg, const float* __restrict__ b0g,
              const float* __restrict__ bfg, char* __restrict__ ws)
{
    __shared__ float R[128 * 36];        // [k][32 pts + pad]
    __shared__ float p1sh[32 * 24];
    const int tid = threadIdx.x;
    const int lane = tid & 63, w = tid >> 6;
    const int u0 = w * 32 + (lane & 7) * 4;
    const int p0 = (lane >> 3) * 4;
    const int L = blockIdx.x / 34;
    const int pb = (blockIdx.x % 34) << 5;

    const float* WT  = (const float*)(ws + WT_OFF);
    const float* WFT = (const float*)(ws + WFT_OFF);
    const float* ws0 = (const float*)(ws + WS0_OFF);
    float* tab = (float*)(ws + TAB_OFF);

    float H[4][4];
    {
        float sp[4] = {gridval(pb + p0), gridval(pb + p0 + 1),
                       gridval(pb + p0 + 2), gridval(pb + p0 + 3)};
        float4 a0 = *(const float4*)(ws0 + L * 128 + u0);
        float4 c0 = *(const float4*)(b0g + L * 128 + u0);
        float aj[4] = {a0.x, a0.y, a0.z, a0.w};
        float cj[4] = {c0.x, c0.y, c0.z, c0.w};
#pragma unroll
        for (int j = 0; j < 4; ++j) {
#pragma unroll
            for (int p = 0; p < 4; ++p) H[j][p] = fmaf(aj[j], sp[p], cj[j]);
            float4 v = {fmaxf(H[j][0], 0.f), fmaxf(H[j][1], 0.f),
                        fmaxf(H[j][2], 0.f), fmaxf(H[j][3], 0.f)};
            *(float4*)(&R[(u0 + j) * 36 + p0]) = v;
        }
    }
    __syncthreads();

#pragma unroll 1
    for (int st = 0; st < 4; ++st) {
        const float* Wst = WT + (L * 4 + st) * 16384;
        const float* bb  = bresg + (L * 4 + st) * 128;
        float acc[4][4];
        {
            float4 b0v = *(const float4*)(bb + u0);
            float bj[4] = {b0v.x, b0v.y, b0v.z, b0v.w};
#pragma unroll
            for (int j = 0; j < 4; ++j)
#pragma unroll
                for (int p = 0; p < 4; ++p) acc[j][p] = bj[j];
        }
#pragma unroll 4
        for (int k = 0; k < 128; ++k) {
            float4 w0 = *(const float4*)(Wst + k * 128 + u0);
            float4 r  = *(const float4*)(&R[k * 36 + p0]);
            float wj[4] = {w0.x, w0.y, w0.z, w0.w};
            float rp[4] = {r.x, r.y, r.z, r.w};
#pragma unroll
            for (int j = 0; j < 4; ++j)
#pragma unroll
                for (int p = 0; p < 4; ++p)
                    acc[j][p] = fmaf(wj[j], rp[p], acc[j][p]);
        }
        if (st == 1 || st == 3) {
#pragma unroll
            for (int j = 0; j < 4; ++j)
#pragma unroll
                for (int p = 0; p < 4; ++p) H[j][p] += acc[j][p];
        }
        __syncthreads();
#pragma unroll
        for (int j = 0; j < 4; ++j) {
            float4 v;
            if (st == 0 || st == 2) {
                v = (float4){fmaxf(acc[j][0], 0.f), fmaxf(acc[j][1], 0.f),
                             fmaxf(acc[j][2], 0.f), fmaxf(acc[j][3], 0.f)};
            } else if (st == 1) {
                v = (float4){fmaxf(H[j][0], 0.f), fmaxf(H[j][1], 0.f),
                             fmaxf(H[j][2], 0.f), fmaxf(H[j][3], 0.f)};
            } else {
                v = (float4){H[j][0], H[j][1], H[j][2], H[j][3]};
            }
            *(float4*)(&R[(u0 + j) * 36 + p0]) = v;
        }
        __syncthreads();
    }

    // projection -> p1sh
    {
        const int o = tid & 31, pg4 = tid >> 5;
        float pacc[4] = {0.f, 0.f, 0.f, 0.f};
#pragma unroll 4
        for (int k = 0; k < 128; ++k) {
            float wf = WFT[(L * 128 + k) * 32 + o];
            float4 ra = *(const float4*)(&R[k * 36 + pg4 * 4]);
            pacc[0] = fmaf(wf, ra.x, pacc[0]);
            pacc[1] = fmaf(wf, ra.y, pacc[1]);
            pacc[2] = fmaf(wf, ra.z, pacc[2]);
            pacc[3] = fmaf(wf, ra.w, pacc[3]);
        }
        if (o < 23) {
            float bias = bfg[L * 46 + 23 + o];
#pragma unroll
            for (int p = 0; p < 4; ++p)
                p1sh[(pg4 * 4 + p) * 24 + o] = pacc[p] + bias;
        }
    }
    __syncthreads();

    // knot phase
    if (tid < 32) {
        float pp[23];
#pragma unroll
        for (int j = 0; j < 23; ++j) pp[j] = p1sh[tid * 24 + j];
        float cw[9], ch[9], d[9];
        knots_from_p(pp, cw, ch, d);
        float out[24];
#pragma unroll
        for (int i = 0; i < 8; ++i) out[i] = cw[i + 1];
#pragma unroll
        for (int i = 0; i < 8; ++i) out[8 + i] = ch[i + 1];
#pragma unroll
        for (int i = 0; i < 7; ++i) out[16 + i] = d[i + 1];
        out[23] = gridval(pb + tid);
        float4* dst = (float4*)(tab + (L * LROW + pb + tid) * TROW);
#pragma unroll
        for (int i = 0; i < 6; ++i)
            dst[i] = ((const float4*)out)[i];
    }
}

// ------------- kernel 3: per-sample flow; uniform constants via scalar loads -------------
extern "C" __global__ __launch_bounds__(256, 4)
void nsf_main(const float* __restrict__ z0g, const float* __restrict__ xg,
              const float* __restrict__ sgg,
              const float* __restrict__ n1w1, const float* __restrict__ n1b1,
              const float* __restrict__ n1w2, const float* __restrict__ n1b2,
              const float* __restrict__ n2w1, const float* __restrict__ n2b1,
              const float* __restrict__ n2w2, const float* __restrict__ n2b2,
              const char* __restrict__ ws, float* __restrict__ outg)
{
    const float* tab  = (const float*)(ws + TAB_OFF);
    const float* recg = (const float*)(ws + REC_OFF);   // block-uniform -> s_load path

    const int tid = threadIdx.x;
    int sA[2];
    sA[0] = blockIdx.x * 512 + tid;
    sA[1] = sA[0] + 256;

    float zz0[2], zz1[2], ld[2] = {0.f, 0.f};
    {
        float za[2], zb[2], xa[2], xb[2], sg[2];
#pragma unroll
        for (int i = 0; i < 2; ++i) {
            za[i] = z0g[2 * sA[i]]; zb[i] = z0g[2 * sA[i] + 1];
            xa[i] = xg[2 * sA[i]];  xb[i] = xg[2 * sA[i] + 1];
            sg[i] = sgg[sA[i]];
        }
        float t0[2] = {n1b2[0], n1b2[0]}, t1[2] = {n1b2[1], n1b2[1]};
#pragma unroll
        for (int m = 0; m < 32; ++m) {
            float w1 = n1w1[m], b1 = n1b1[m], w2a = n1w2[m], w2b = n1w2[32 + m];
#pragma unroll
            for (int i = 0; i < 2; ++i) {
                float hm = fmaf(sg[i], w1, b1);
                hm = hm * fastrcp(1.f + __expf(-hm));
                t0[i] = fmaf(hm, w2a, t0[i]);
                t1[i] = fmaf(hm, w2b, t1[i]);
            }
        }
        float u0[2] = {n2b2[0], n2b2[0]}, u1[2] = {n2b2[1], n2b2[1]};
#pragma unroll
        for (int m = 0; m < 32; ++m) {
            float wa = n2w1[4 * m], wb = n2w1[4 * m + 1];
            float wc = n2w1[4 * m + 2], wd = n2w1[4 * m + 3];
            float b1 = n2b1[m], w2a = n2w2[m], w2b = n2w2[32 + m];
#pragma unroll
            for (int i = 0; i < 2; ++i) {
                float hm = za[i] * wa + zb[i] * wb + xa[i] * wc + xb[i] * wd + b1;
                hm = hm * fastrcp(1.f + __expf(-hm));
                u0[i] = fmaf(hm, w2a, u0[i]);
                u1[i] = fmaf(hm, w2b, u1[i]);
            }
        }
#pragma unroll
        for (int i = 0; i < 2; ++i) { zz0[i] = u0[i] + t0[i]; zz1[i] = u1[i] + t1[i]; }
    }

    for (int L = 0; L < 16; ++L) {
        const float* rec = recg + L * 40;     // uniform address -> scalar loads, K$-hot
        float out0[2], ldp0[2];
#pragma unroll
        for (int i = 0; i < 2; ++i)
            rqs_knots(zz0[i], rec, out0[i], ldp0[i]);

        const float4* r4[2];
#pragma unroll
        for (int i = 0; i < 2; ++i) {
            int pos = min(max(cnt_grid_le_fast(out0[i]) - 1, 0), NGRID - 2);
            r4[i] = (const float4*)(tab + (L * LROW + pos) * TROW);
        }
        float4 q0[2][6], q1[2][6];
#pragma unroll
        for (int i = 0; i < 2; ++i)
#pragma unroll
            for (int j = 0; j < 6; ++j) { q0[i][j] = r4[i][j]; q1[i][j] = r4[i][j + 6]; }

        float out1[2], ldp1[2];
#pragma unroll
        for (int i = 0; i < 2; ++i) {
            float e0 = q0[i][5].w, e1 = q1[i][5].w;
            float de = e1 - e0;
            float tt = (de > 1e-9f) ? (out0[i] - e0) * fastrcp(de) : 0.f;

            float cw[9], ch[9], d[9];
            cw[0] = -3.f; ch[0] = -3.f; d[0] = 1.f; d[8] = 1.f;
#pragma unroll
            for (int j = 0; j < 2; ++j) {
                cw[4 * j + 1] = fmaf(tt, q1[i][j].x - q0[i][j].x, q0[i][j].x);
                cw[4 * j + 2] = fmaf(tt, q1[i][j].y - q0[i][j].y, q0[i][j].y);
                cw[4 * j + 3] = fmaf(tt, q1[i][j].z - q0[i][j].z, q0[i][j].z);
                cw[4 * j + 4] = fmaf(tt, q1[i][j].w - q0[i][j].w, q0[i][j].w);
                ch[4 * j + 1] = fmaf(tt, q1[i][j + 2].x - q0[i][j + 2].x, q0[i][j + 2].x);
                ch[4 * j + 2] = fmaf(tt, q1[i][j + 2].y - q0[i][j + 2].y, q0[i][j + 2].y);
                ch[4 * j + 3] = fmaf(tt, q1[i][j + 2].z - q0[i][j + 2].z, q0[i][j + 2].z);
                ch[4 * j + 4] = fmaf(tt, q1[i][j + 2].w - q0[i][j + 2].w, q0[i][j + 2].w);
            }
            d[1] = fmaf(tt, q1[i][4].x - q0[i][4].x, q0[i][4].x);
            d[2] = fmaf(tt, q1[i][4].y - q0[i][4].y, q0[i][4].y);
            d[3] = fmaf(tt, q1[i][4].z - q0[i][4].z, q0[i][4].z);
            d[4] = fmaf(tt, q1[i][4].w - q0[i][4].w, q0[i][4].w);
            d[5] = fmaf(tt, q1[i][5].x - q0[i][5].x, q0[i][5].x);
            d[6] = fmaf(tt, q1[i][5].y - q0[i][5].y, q0[i][5].y);
            d[7] = fmaf(tt, q1[i][5].z - q0[i][5].z, q0[i][5].z);

            rqs_from_knots(zz1[i], cw, ch, d, out1[i], ldp1[i]);
        }

#pragma unroll
        for (int i = 0; i < 2; ++i) {
            ld[i] += ldp0[i] + ldp1[i];
            float v0 = out0[i] - rec[31], v1 = out1[i] - rec[32];
            zz0[i] = fmaf(v0, rec[27], v1 * rec[28]);
            zz1[i] = fmaf(v0, rec[29], v1 * rec[30]);
        }
    }

    float ldc = *(const float*)(ws + LDC_OFF);
#pragma unroll
    for (int i = 0; i < 2; ++i) {
        outg[2 * sA[i]] = zz0[i];
        outg[2 * sA[i] + 1] = zz1[i];
        outg[2 * NBATCH + sA[i]] = ld[i] - ldc;
    }
}

extern "C" void kernel_launch(void* const* d_in, const int* in_sizes, int n_in,
                              void* d_out, int out_size, void* d_ws, size_t ws_size,
                              hipStream_t stream)
{
    const float* z0g  = (const float*)d_in[0];
    const float* xg   = (const float*)d_in[1];
    const float* sgg  = (const float*)d_in[2];
    const float* n1w1 = (const float*)d_in[3];
    const float* n1b1 = (const float*)d_in[4];
    const float* n1w2 = (const float*)d_in[5];
    const float* n1b2 = (const float*)d_in[6];
    const float* n2w1 = (const float*)d_in[7];
    const float* n2b1 = (const float*)d_in[8];
    const float* n2w2 = (const float*)d_in[9];
    const float* n2b2 = (const float*)d_in[10];
    const float* W0g  = (const float*)d_in[11];
    const float* b0g  = (const float*)d_in[12];
    const float* Wres = (const float*)d_in[13];
    const float* bres = (const float*)d_in[14];
    const float* Wfg  = (const float*)d_in[15];
    const float* bfg  = (const float*)d_in[16];
    const float* lul  = (const float*)d_in[17];
    const float* luu  = (const float*)d_in[18];
    const float* lud  = (const float*)d_in[19];
    const float* lub  = (const float*)d_in[20];
    const int*   perms= (const int*)d_in[21];
    float* outg = (float*)d_out;
    char* ws = (char*)d_ws;

    nsf_prep<<<272, 256, 0, stream>>>(Wres, Wfg, W0g, b0g, bfg, lul, luu, lud, lub, perms, ws);
    nsf_eval<<<544, 256, 0, stream>>>(bres, b0g, bfg, ws);
    nsf_main<<<NBATCH / 512, 256, 0, stream>>>(z0g, xg, sgg,
                                               n1w1, n1b1, n1w2, n1b2,
                                               n2w1, n2b1, n2w2, n2b2,
                                               ws, outg);
}

// Round 20
// 256.186 us; speedup vs baseline: 1.0222x; 1.0222x over previous
//
#include <hip/hip_runtime.h>
#include <math.h>

#define NBATCH 262144
#define INVSQH 0.08838834764831845f   // 1/sqrt(128)

#define LROW  1088                    // table rows per layer
#define NGRID 1088                    // grid points: 192 coarse | 704 dense | 192 coarse
#define TROW  24

// ---- workspace layout (bytes) ----
#define WT_OFF   0          // Wres transposed [sidx][k][u] f32: 4,194,304
#define WFT_OFF  4194304    // WfT [L][k][32] f32 (o>=23 zero): 262,144
#define WS0_OFF  4456448    // W0 col0 [L][128] f32: 8,192
#define TAB_OFF  4464640    // knot table [L][1088][24] f32: cw1..8|ch1..8|d1..7|gridv
#define REC_OFF  7610368    // 16*40 f32
#define LDC_OFF  7612928    // 1 f32

// ---- fast approx ops (<=2 ulp; margin vs threshold ~9x) ----
__device__ __forceinline__ float fastrcp(float x) {
#if __has_builtin(__builtin_amdgcn_rcpf)
    return __builtin_amdgcn_rcpf(x);
#else
    return 1.f / x;
#endif
}
__device__ __forceinline__ float fastdiv(float a, float b) { return a * fastrcp(b); }
__device__ __forceinline__ float fastsqrt(float x) {
#if __has_builtin(__builtin_amdgcn_sqrtf)
    return __builtin_amdgcn_sqrtf(x);
#else
    return sqrtf(x);
#endif
}

__device__ __forceinline__ float softplusf(float x) {
    return (x > 15.f) ? x : __logf(1.f + __expf(x));
}

// implicit sorted grid: low coarse(192 @0.25) | dense(704 @0.025) | high coarse(192 @0.25)
__device__ __forceinline__ float gridval(int i) {
    float v = -56.8f + i * 0.25f;
    if (i >= 192) v = -8.8f + (i - 192) * 0.025f;
    if (i >= 896) v = 9.05f + (i - 896) * 0.25f;
    return v;
}
// closed-form count of grid values <= x; off-by-one benign (t from stored endpoints)
__device__ __forceinline__ int cnt_grid_le_fast(float x) {
    if (x < -56.8f) return 0;
    if (x < -8.8f)  return min((int)floorf((x + 56.8f) * 4.0f) + 1, 192);
    if (x < 9.05f)  return 192 + min((int)floorf((x + 8.8f) * 40.0f) + 1, 704);
    return 896 + min((int)floorf((x - 9.05f) * 4.0f) + 1, 192);
}

__device__ __forceinline__ void rqs_solve(float y, float yc, float yk, float hk, float xk,
                                          float wk, float dk, float dk1,
                                          float& xout, float& ldout)
{
    float sk = fastdiv(hk, wk);
    float dy = yc - yk;
    float t2 = dk + dk1 - 2.f * sk;
    float av = dy * t2 + hk * (sk - dk);
    float bv = hk * dk - dy * t2;
    float cv = -sk * dy;
    float disc = fmaxf(bv * bv - 4.f * av * cv, 0.f);
    float theta = 2.f * cv * fastrcp(-bv - fastsqrt(disc));
    float xo = fmaf(theta, wk, xk);
    float om = 1.f - theta;
    float denom = fmaf(t2, theta * om, sk);
    float dnum = sk * sk * (dk1 * theta * theta + 2.f * sk * theta * om + dk * om * om);
    float rden = fastrcp(denom);
    float ldf = __logf(dnum * rden * rden);       // log(dnum) - 2 log(denom)
    bool inside = (y >= -3.f) && (y <= 3.f);
    xout  = inside ? xo : y;
    ldout = inside ? -ldf : 0.f;
}

// knots from raw params p[0..22] (eval's knot phase)
__device__ __forceinline__ void knots_from_p(const float* __restrict__ p,
                                             float* __restrict__ cw,
                                             float* __restrict__ ch,
                                             float* __restrict__ d)
{
    float uw[8], uh[8];
#pragma unroll
    for (int j = 0; j < 8; ++j) uw[j] = p[j] * INVSQH;
#pragma unroll
    for (int j = 0; j < 8; ++j) uh[j] = p[8 + j] * INVSQH;
    float mw = uw[0], mh = uh[0];
#pragma unroll
    for (int j = 1; j < 8; ++j) { mw = fmaxf(mw, uw[j]); mh = fmaxf(mh, uh[j]); }
    float ew[8], eh[8], sw = 0.f, sh = 0.f;
#pragma unroll
    for (int j = 0; j < 8; ++j) {
        ew[j] = __expf(uw[j] - mw); sw += ew[j];
        eh[j] = __expf(uh[j] - mh); sh += eh[j];
    }
    float isw = 0.992f * fastrcp(sw), ish = 0.992f * fastrcp(sh);
    cw[0] = -3.f; ch[0] = -3.f;
    float aw = 0.f, ah = 0.f;
#pragma unroll
    for (int j = 0; j < 8; ++j) {
        aw += 0.001f + ew[j] * isw;
        ah += 0.001f + eh[j] * ish;
        cw[j + 1] = 6.f * aw - 3.f;
        ch[j + 1] = 6.f * ah - 3.f;
    }
    cw[8] = 3.f; ch[8] = 3.f;
    d[0] = 1.f; d[8] = 1.f;
#pragma unroll
    for (int j = 0; j < 7; ++j) d[j + 1] = 0.001f + softplusf(p[16 + j]);
}

__device__ __forceinline__ void rqs_from_knots(float y, const float* __restrict__ cw,
                                               const float* __restrict__ ch,
                                               const float* __restrict__ d,
                                               float& xout, float& ldout)
{
    float yc = fminf(fmaxf(y, -3.f), 3.f);
    float yk = ch[0], hk = ch[1] - ch[0], xk = cw[0], wk = cw[1] - cw[0];
    float dk = d[0], dk1 = d[1];
#pragma unroll
    for (int j = 1; j < 8; ++j) {
        bool cge = (yc >= ch[j]);
        yk  = cge ? ch[j] : yk;
        hk  = cge ? (ch[j + 1] - ch[j]) : hk;
        xk  = cge ? cw[j] : xk;
        wk  = cge ? (cw[j + 1] - cw[j]) : wk;
        dk  = cge ? d[j] : dk;
        dk1 = cge ? d[j + 1] : dk1;
    }
    rqs_solve(y, yc, yk, hk, xk, wk, dk, dk1, xout, ldout);
}

__device__ __forceinline__ void rqs_knots(float y, const float* __restrict__ rec,
                                          float& xout, float& ldout)
{
    rqs_from_knots(y, rec, rec + 9, rec + 18, xout, ldout);
}

// ------------- kernel 1: weight images (LDS-tiled transpose) + per-layer constants -------------
extern "C" __global__ __launch_bounds__(256)
void nsf_prep(const float* __restrict__ Wresg, const float* __restrict__ Wfg,
              const float* __restrict__ W0g,  const float* __restrict__ b0g,
              const float* __restrict__ bfg,
              const float* __restrict__ lulg, const float* __restrict__ luug,
              const float* __restrict__ ludg, const float* __restrict__ lubg,
              const int* __restrict__ permsg, char* __restrict__ ws)
{
    const int b = blockIdx.x, tid = threadIdx.x;
    float* WT  = (float*)(ws + WT_OFF);
    float* WFT = (float*)(ws + WFT_OFF);
    float* ws0 = (float*)(ws + WS0_OFF);

    if (b < 256) {
        __shared__ float T[64][65];
        const int mat = b >> 2, tr = (b >> 1) & 1, tc = b & 1;
        const float* src = Wresg + mat * 16384;
        float* dst = WT + mat * 16384;
        const int r = tid >> 2, q = tid & 3;        // 64 rows x 4 lanes/row
#pragma unroll
        for (int i = 0; i < 4; ++i) {
            int c4 = q * 4 + i;
            float4 v = *(const float4*)(src + (tr * 64 + r) * 128 + tc * 64 + c4 * 4);
            T[r][c4 * 4 + 0] = v.x; T[r][c4 * 4 + 1] = v.y;
            T[r][c4 * 4 + 2] = v.z; T[r][c4 * 4 + 3] = v.w;
        }
        __syncthreads();
        const int kk = tid >> 2;
#pragma unroll
        for (int i = 0; i < 4; ++i) {
            int u4 = q * 4 + i;
            float4 v;
            v.x = T[u4 * 4 + 0][kk]; v.y = T[u4 * 4 + 1][kk];
            v.z = T[u4 * 4 + 2][kk]; v.w = T[u4 * 4 + 3][kk];
            *(float4*)(dst + (tc * 64 + kk) * 128 + tr * 64 + u4 * 4) = v;
        }
        return;
    }

    const int L = b - 256;
    for (int e = tid; e < 4096; e += 256) {
        int k = e >> 5, o = e & 31;
        WFT[L * 4096 + e] = (o < 23) ? Wfg[(L * 46 + 23 + o) * 128 + k] : 0.f;
    }
    if (tid < 128) ws0[L * 128 + tid] = W0g[L * 256 + 2 * tid];

    if (tid == 0) {
        float* rec = (float*)(ws + REC_OFF) + L * 40;
        const float* p = bfg + L * 46;
        for (int half = 0; half < 2; ++half) {
            float u[8], m = -1e30f;
            for (int j = 0; j < 8; ++j) { u[j] = p[half * 8 + j] * INVSQH; m = fmaxf(m, u[j]); }
            float e[8], ssum = 0.f;
            for (int j = 0; j < 8; ++j) { e[j] = expf(u[j] - m); ssum += e[j]; }
            float cum = 0.f;
            rec[half * 9 + 0] = -3.f;
            for (int j = 0; j < 8; ++j) {
                cum += 0.001f + 0.992f * e[j] / ssum;
                rec[half * 9 + 1 + j] = 6.f * cum - 3.f;
            }
            rec[half * 9 + 8] = 3.f;
        }
        rec[18] = 1.f; rec[26] = 1.f;
        for (int j = 0; j < 7; ++j) {
            float x = p[16 + j];
            rec[19 + j] = 0.001f + ((x > 15.f) ? x : log1pf(expf(x)));
        }
        float x0 = ludg[2 * L], x1 = ludg[2 * L + 1];
        float dg0 = 0.001f + ((x0 > 15.f) ? x0 : log1pf(expf(x0)));
        float dg1 = 0.001f + ((x1 > 15.f) ? x1 : log1pf(expf(x1)));
        float ll = lulg[L], uu = luug[L];
        float det = dg0 * dg1;
        float c00 = (ll * uu + dg1) / det, c01 = -uu / det;
        float c10 = -ll / dg1, c11 = 1.f / dg1;
        int pa = permsg[2 * L], pb2 = permsg[2 * L + 1];
        rec[27] = pa ? c10 : c00;  rec[28] = pa ? c11 : c01;
        rec[29] = pb2 ? c10 : c00; rec[30] = pb2 ? c11 : c01;
        rec[31] = lubg[2 * L];     rec[32] = lubg[2 * L + 1];
    }
    if (L == 0 && tid == 32) {
        float ssum = 0.f;
        for (int l2 = 0; l2 < 16; ++l2) {
            float x0 = ludg[2 * l2], x1 = ludg[2 * l2 + 1];
            float dg0 = 0.001f + ((x0 > 15.f) ? x0 : log1pf(expf(x0)));
            float dg1 = 0.001f + ((x1 > 15.f) ? x1 : log1pf(expf(x1)));
            ssum += logf(dg0) + logf(dg1);
        }
        *(float*)(ws + LDC_OFF) = ssum;
    }
}

// ------------- kernel 2: table evaluation (grid -> knots), 4u x 4p threads -------------
// 544 blocks = 16 layers x 34 chunks of 32 points. Wave w owns u in [32w, 32w+32):
// thread u0 = w*32 + (lane&7)*4 (4 outputs), p0 = (lane>>3)*4 (4 points).
extern "C" __global__ __launch_bounds__(256, 4)
void nsf_eval(const float* __restrict__ bresg, const float* __restrict__ b0g,
              const float* __restrict__ bfg, char* __restrict__ ws)
{
    __shared__ float R[128 * 36];        // [k][32 pts + pad]
    __shared__ float p1sh[32 * 24];
    const int tid = threadIdx.x;
    const int lane = tid & 63, w = tid >> 6;
    const int u0 = w * 32 + (lane & 7) * 4;
    const int p0 = (lane >> 3) * 4;
    const int L = blockIdx.x / 34;
    const int pb = (blockIdx.x % 34) << 5;

    const float* WT  = (const float*)(ws + WT_OFF);
    const float* WFT = (const float*)(ws + WFT_OFF);
    const float* ws0 = (const float*)(ws + WS0_OFF);
    float* tab = (float*)(ws + TAB_OFF);

    float H[4][4];
    {
        float sp[4] = {gridval(pb + p0), gridval(pb + p0 + 1),
                       gridval(pb + p0 + 2), gridval(pb + p0 + 3)};
        float4 a0 = *(const float4*)(ws0 + L * 128 + u0);
        float4 c0 = *(const float4*)(b0g + L * 128 + u0);
        float aj[4] = {a0.x, a0.y, a0.z, a0.w};
        float cj[4] = {c0.x, c0.y, c0.z, c0.w};
#pragma unroll
        for (int j = 0; j < 4; ++j) {
#pragma unroll
            for (int p = 0; p < 4; ++p) H[j][p] = fmaf(aj[j], sp[p], cj[j]);
            float4 v = {fmaxf(H[j][0], 0.f), fmaxf(H[j][1], 0.f),
                        fmaxf(H[j][2], 0.f), fmaxf(H[j][3], 0.f)};
            *(float4*)(&R[(u0 + j) * 36 + p0]) = v;
        }
    }
    __syncthreads();

#pragma unroll 1
    for (int st = 0; st < 4; ++st) {
        const float* Wst = WT + (L * 4 + st) * 16384;
        const float* bb  = bresg + (L * 4 + st) * 128;
        float acc[4][4];
        {
            float4 b0v = *(const float4*)(bb + u0);
            float bj[4] = {b0v.x, b0v.y, b0v.z, b0v.w};
#pragma unroll
            for (int j = 0; j < 4; ++j)
#pragma unroll
                for (int p = 0; p < 4; ++p) acc[j][p] = bj[j];
        }
#pragma unroll 4
        for (int k = 0; k < 128; ++k) {
            float4 w0 = *(const float4*)(Wst + k * 128 + u0);
            float4 r  = *(const float4*)(&R[k * 36 + p0]);
            float wj[4] = {w0.x, w0.y, w0.z, w0.w};
            float rp[4] = {r.x, r.y, r.z, r.w};
#pragma unroll
            for (int j = 0; j < 4; ++j)
#pragma unroll
                for (int p = 0; p < 4; ++p)
                    acc[j][p] = fmaf(wj[j], rp[p], acc[j][p]);
        }
        if (st == 1 || st == 3) {
#pragma unroll
            for (int j = 0; j < 4; ++j)
#pragma unroll
                for (int p = 0; p < 4; ++p) H[j][p] += acc[j][p];
        }
        __syncthreads();
#pragma unroll
        for (int j = 0; j < 4; ++j) {
            float4 v;
            if (st == 0 || st == 2) {
                v = (float4){fmaxf(acc[j][0], 0.f), fmaxf(acc[j][1], 0.f),
                             fmaxf(acc[j][2], 0.f), fmaxf(acc[j][3], 0.f)};
            } else if (st == 1) {
                v = (float4){fmaxf(H[j][0], 0.f), fmaxf(H[j][1], 0.f),
                             fmaxf(H[j][2], 0.f), fmaxf(H[j][3], 0.f)};
            } else {
                v = (float4){H[j][0], H[j][1], H[j][2], H[j][3]};
            }
            *(float4*)(&R[(u0 + j) * 36 + p0]) = v;
        }
        __syncthreads();
    }

    // projection -> p1sh
    {
        const int o = tid & 31, pg4 = tid >> 5;
        float pacc[4] = {0.f, 0.f, 0.f, 0.f};
#pragma unroll 4
        for (int k = 0; k < 128; ++k) {
            float wf = WFT[(L * 128 + k) * 32 + o];
            float4 ra = *(const float4*)(&R[k * 36 + pg4 * 4]);
            pacc[0] = fmaf(wf, ra.x, pacc[0]);
            pacc[1] = fmaf(wf, ra.y, pacc[1]);
            pacc[2] = fmaf(wf, ra.z, pacc[2]);
            pacc[3] = fmaf(wf, ra.w, pacc[3]);
        }
        if (o < 23) {
            float bias = bfg[L * 46 + 23 + o];
#pragma unroll
            for (int p = 0; p < 4; ++p)
                p1sh[(pg4 * 4 + p) * 24 + o] = pacc[p] + bias;
        }
    }
    __syncthreads();

    // knot phase
    if (tid < 32) {
        float pp[23];
#pragma unroll
        for (int j = 0; j < 23; ++j) pp[j] = p1sh[tid * 24 + j];
        float cw[9], ch[9], d[9];
        knots_from_p(pp, cw, ch, d);
        float out[24];
#pragma unroll
        for (int i = 0; i < 8; ++i) out[i] = cw[i + 1];
#pragma unroll
        for (int i = 0; i < 8; ++i) out[8 + i] = ch[i + 1];
#pragma unroll
        for (int i = 0; i < 7; ++i) out[16 + i] = d[i + 1];
        out[23] = gridval(pb + tid);
        float4* dst = (float4*)(tab + (L * LROW + pb + tid) * TROW);
#pragma unroll
        for (int i = 0; i < 6; ++i)
            dst[i] = ((const float4*)out)[i];
    }
}

// ------------- kernel 3: per-sample flow; 2 samples/thread for chain ILP -------------
extern "C" __global__ __launch_bounds__(256, 4)
void nsf_main(const float* __restrict__ z0g, const float* __restrict__ xg,
              const float* __restrict__ sgg,
              const float* __restrict__ n1w1, const float* __restrict__ n1b1,
              const float* __restrict__ n1w2, const float* __restrict__ n1b2,
              const float* __restrict__ n2w1, const float* __restrict__ n2b1,
              const float* __restrict__ n2w2, const float* __restrict__ n2b2,
              const char* __restrict__ ws, float* __restrict__ outg)
{
    __shared__ float recs_s[16 * 40];

    const float* tab  = (const float*)(ws + TAB_OFF);
    const float* recg = (const float*)(ws + REC_OFF);

    const int tid = threadIdx.x;
    int sA[2];
    sA[0] = blockIdx.x * 512 + tid;
    sA[1] = sA[0] + 256;

    for (int i = tid; i < 640; i += 256) recs_s[i] = recg[i];
    __syncthreads();

    float zz0[2], zz1[2], ld[2] = {0.f, 0.f};
    {
        float za[2], zb[2], xa[2], xb[2], sg[2];
#pragma unroll
        for (int i = 0; i < 2; ++i) {
            za[i] = z0g[2 * sA[i]]; zb[i] = z0g[2 * sA[i] + 1];
            xa[i] = xg[2 * sA[i]];  xb[i] = xg[2 * sA[i] + 1];
            sg[i] = sgg[sA[i]];
        }
        float t0[2] = {n1b2[0], n1b2[0]}, t1[2] = {n1b2[1], n1b2[1]};
#pragma unroll
        for (int m = 0; m < 32; ++m) {
            float w1 = n1w1[m], b1 = n1b1[m], w2a = n1w2[m], w2b = n1w2[32 + m];
#pragma unroll
            for (int i = 0; i < 2; ++i) {
                float hm = fmaf(sg[i], w1, b1);
                hm = hm * fastrcp(1.f + __expf(-hm));
                t0[i] = fmaf(hm, w2a, t0[i]);
                t1[i] = fmaf(hm, w2b, t1[i]);
            }
        }
        float u0[2] = {n2b2[0], n2b2[0]}, u1[2] = {n2b2[1], n2b2[1]};
#pragma unroll
        for (int m = 0; m < 32; ++m) {
            float wa = n2w1[4 * m], wb = n2w1[4 * m + 1];
            float wc = n2w1[4 * m + 2], wd = n2w1[4 * m + 3];
            float b1 = n2b1[m], w2a = n2w2[m], w2b = n2w2[32 + m];
#pragma unroll
            for (int i = 0; i < 2; ++i) {
                float hm = za[i] * wa + zb[i] * wb + xa[i] * wc + xb[i] * wd + b1;
                hm = hm * fastrcp(1.f + __expf(-hm));
                u0[i] = fmaf(hm, w2a, u0[i]);
                u1[i] = fmaf(hm, w2b, u1[i]);
            }
        }
#pragma unroll
        for (int i = 0; i < 2; ++i) { zz0[i] = u0[i] + t0[i]; zz1[i] = u1[i] + t1[i]; }
    }

    for (int L = 0; L < 16; ++L) {
        const float* rec = recs_s + L * 40;
        float out0[2], ldp0[2];
#pragma unroll
        for (int i = 0; i < 2; ++i)
            rqs_knots(zz0[i], rec, out0[i], ldp0[i]);

        const float4* r4[2];
#pragma unroll
        for (int i = 0; i < 2; ++i) {
            int pos = min(max(cnt_grid_le_fast(out0[i]) - 1, 0), NGRID - 2);
            r4[i] = (const float4*)(tab + (L * LROW + pos) * TROW);
        }
        float4 q0[2][6], q1[2][6];
#pragma unroll
        for (int i = 0; i < 2; ++i)
#pragma unroll
            for (int j = 0; j < 6; ++j) { q0[i][j] = r4[i][j]; q1[i][j] = r4[i][j + 6]; }

        float out1[2], ldp1[2];
#pragma unroll
        for (int i = 0; i < 2; ++i) {
            float e0 = q0[i][5].w, e1 = q1[i][5].w;
            float de = e1 - e0;
            float tt = (de > 1e-9f) ? (out0[i] - e0) * fastrcp(de) : 0.f;

            float cw[9], ch[9], d[9];
            cw[0] = -3.f; ch[0] = -3.f; d[0] = 1.f; d[8] = 1.f;
#pragma unroll
            for (int j = 0; j < 2; ++j) {
                cw[4 * j + 1] = fmaf(tt, q1[i][j].x - q0[i][j].x, q0[i][j].x);
                cw[4 * j + 2] = fmaf(tt, q1[i][j].y - q0[i][j].y, q0[i][j].y);
                cw[4 * j + 3] = fmaf(tt, q1[i][j].z - q0[i][j].z, q0[i][j].z);
                cw[4 * j + 4] = fmaf(tt, q1[i][j].w - q0[i][j].w, q0[i][j].w);
                ch[4 * j + 1] = fmaf(tt, q1[i][j + 2].x - q0[i][j + 2].x, q0[i][j + 2].x);
                ch[4 * j + 2] = fmaf(tt, q1[i][j + 2].y - q0[i][j + 2].y, q0[i][j + 2].y);
                ch[4 * j + 3] = fmaf(tt, q1[i][j + 2].z - q0[i][j + 2].z, q0[i][j + 2].z);
                ch[4 * j + 4] = fmaf(tt, q1[i][j + 2].w - q0[i][j + 2].w, q0[i][j + 2].w);
            }
            d[1] = fmaf(tt, q1[i][4].x - q0[i][4].x, q0[i][4].x);
            d[2] = fmaf(tt, q1[i][4].y - q0[i][4].y, q0[i][4].y);
            d[3] = fmaf(tt, q1[i][4].z - q0[i][4].z, q0[i][4].z);
            d[4] = fmaf(tt, q1[i][4].w - q0[i][4].w, q0[i][4].w);
            d[5] = fmaf(tt, q1[i][5].x - q0[i][5].x, q0[i][5].x);
            d[6] = fmaf(tt, q1[i][5].y - q0[i][5].y, q0[i][5].y);
            d[7] = fmaf(tt, q1[i][5].z - q0[i][5].z, q0[i][5].z);

            rqs_from_knots(zz1[i], cw, ch, d, out1[i], ldp1[i]);
        }

#pragma unroll
        for (int i = 0; i < 2; ++i) {
            ld[i] += ldp0[i] + ldp1[i];
            float v0 = out0[i] - rec[31], v1 = out1[i] - rec[32];
            zz0[i] = fmaf(v0, rec[27], v1 * rec[28]);
            zz1[i] = fmaf(v0, rec[29], v1 * rec[30]);
        }
    }

    float ldc = *(const float*)(ws + LDC_OFF);
#pragma unroll
    for (int i = 0; i < 2; ++i) {
        outg[2 * sA[i]] = zz0[i];
        outg[2 * sA[i] + 1] = zz1[i];
        outg[2 * NBATCH + sA[i]] = ld[i] - ldc;
    }
}

extern "C" void kernel_launch(void* const* d_in, const int* in_sizes, int n_in,
                              void* d_out, int out_size, void* d_ws, size_t ws_size,
                              hipStream_t stream)
{
    const float* z0g  = (const float*)d_in[0];
    const float* xg   = (const float*)d_in[1];
    const float* sgg  = (const float*)d_in[2];
    const float* n1w1 = (const float*)d_in[3];
    const float* n1b1 = (const float*)d_in[4];
    const float* n1w2 = (const float*)d_in[5];
    const float* n1b2 = (const float*)d_in[6];
    const float* n2w1 = (const float*)d_in[7];
    const float* n2b1 = (const float*)d_in[8];
    const float* n2w2 = (const float*)d_in[9];
    const float* n2b2 = (const float*)d_in[10];
    const float* W0g  = (const float*)d_in[11];
    const float* b0g  = (const float*)d_in[12];
    const float* Wres = (const float*)d_in[13];
    const float* bres = (const float*)d_in[14];
    const float* Wfg  = (const float*)d_in[15];
    const float* bfg  = (const float*)d_in[16];
    const float* lul  = (const float*)d_in[17];
    const float* luu  = (const float*)d_in[18];
    const float* lud  = (const float*)d_in[19];
    const float* lub  = (const float*)d_in[20];
    const int*   perms= (const int*)d_in[21];
    float* outg = (float*)d_out;
    char* ws = (char*)d_ws;

    nsf_prep<<<272, 256, 0, stream>>>(Wres, Wfg, W0g, b0g, bfg, lul, luu, lud, lub, perms, ws);
    nsf_eval<<<544, 256, 0, stream>>>(bres, b0g, bfg, ws);
    nsf_main<<<NBATCH / 512, 256, 0, stream>>>(z0g, xg, sgg,
                                               n1w1, n1b1, n1w2, n1b2,
                                               n2w1, n2b1, n2w2, n2b2,
                                               ws, outg);
}